// Round 2
// baseline (258.155 us; speedup 1.0000x reference)
//
#include <hip/hip_runtime.h>

// ---------------------------------------------------------------------------
// DWT autoencoder round trip. Level-2 dwt2+idwt2 cancel exactly -> LL1r==LL1.
//   K1: haar dwt level1 of x -> LL1 (B,3,256,256)  +  conv3x3 s2 of the
//       9 detail bands -> y (B,9,128,128)
//   K2: convT4x4 s2 of y -> l1 bands, fused with idwt2(LL1, l1) -> out
// B=32, C=3, H=W=512.
// R1 change: K2 restructured so only 18 accumulators are live (di-parity
// outer loop) -> fits VGPRs, no AGPR/scratch shuffling; float4 epilogue.
// ---------------------------------------------------------------------------

#define BB 32

__global__ __launch_bounds__(256) void k1_dwt_down(
    const float* __restrict__ x,     // (B,3,512,512)
    const float* __restrict__ dw,    // (9,9,3,3) OIHW
    const float* __restrict__ db,    // (9)
    float* __restrict__ LL1,         // (B,3,256,256)
    float* __restrict__ y)           // (B,9,128,128)
{
    __shared__ float lvl[9][33][33];   // [c*3+band][row][col], band: LH,HL,HH

    const int t    = threadIdx.x;
    const int b    = blockIdx.x >> 6;
    const int tile = blockIdx.x & 63;
    const int i0   = (tile >> 3) << 4;   // y tile origin (128-res)
    const int j0   = (tile & 7) << 4;
    const int gr0  = 2 * i0 - 1;         // level1 row of local row 0
    const int gc0  = 2 * j0 - 1;

    // ---- stage 1: DWT level 1 into LDS (+ LL1 interior to global) ----
    for (int item = t; item < 3 * 1089; item += 256) {
        const int ch  = item / 1089;
        int rem       = item - ch * 1089;
        const int lr  = rem / 33;
        const int lc  = rem - lr * 33;
        const int r   = gr0 + lr;        // level1 row in [-1, 255]
        const int c   = gc0 + lc;
        float x00 = 0.f, x01 = 0.f, x10 = 0.f, x11 = 0.f;
        if (r >= 0 && c >= 0 && r < 256 && c < 256) {
            const float* xp = x + (((size_t)b * 3 + ch) * 512 + 2 * r) * 512 + 2 * c;
            const float2 v0 = *reinterpret_cast<const float2*>(xp);
            const float2 v1 = *reinterpret_cast<const float2*>(xp + 512);
            x00 = v0.x; x01 = v0.y; x10 = v1.x; x11 = v1.y;
        }
        const float s0 = x00 + x01, d0 = x00 - x01;
        const float s1 = x10 + x11, d1 = x10 - x11;
        lvl[ch * 3 + 0][lr][lc] = (s0 - s1) * 0.5f;  // LH
        lvl[ch * 3 + 1][lr][lc] = (d0 + d1) * 0.5f;  // HL
        lvl[ch * 3 + 2][lr][lc] = (d0 - d1) * 0.5f;  // HH
        if (lr >= 1 && lc >= 1) {
            LL1[(((size_t)b * 3 + ch) * 256 + r) * 256 + c] = (s0 + s1) * 0.5f;
        }
    }
    __syncthreads();

    // ---- stage 2: 3x3 stride-2 conv, 9 in ch -> 9 out ch ----
    const int ti = t >> 4;   // 0..15
    const int tj = t & 15;
    float acc[9];
#pragma unroll
    for (int o = 0; o < 9; ++o) acc[o] = db[o];

    for (int cin = 0; cin < 9; ++cin) {
        float v[3][3];
#pragma unroll
        for (int a = 0; a < 3; ++a)
#pragma unroll
            for (int q = 0; q < 3; ++q)
                v[a][q] = lvl[cin][2 * ti + a][2 * tj + q];
#pragma unroll
        for (int a = 0; a < 3; ++a)
#pragma unroll
            for (int q = 0; q < 3; ++q) {
                const float vv = v[a][q];
#pragma unroll
                for (int o = 0; o < 9; ++o)
                    acc[o] += vv * dw[o * 81 + cin * 9 + a * 3 + q];  // uniform -> s_load
            }
    }
#pragma unroll
    for (int o = 0; o < 9; ++o)
        y[(((size_t)b * 9 + o) * 128 + (i0 + ti)) * 128 + (j0 + tj)] = acc[o];
}

// K2: one block = one batch image, a 32x32 tile at 256-res (=> 64x64 output
// pixels at 512-res), all 3 colors. Thread t owns the 2x2 quad of 256-res
// positions (r0+2*i2+di, c0+2*j2+dj); di is an OUTER compile-time loop so
// only acc[2][9] (18 regs) is live at once. dj kept in registers so the
// epilogue writes 4 consecutive output columns -> float4 stores.
__global__ __launch_bounds__(256) void k2_up_idwt(
    const float* __restrict__ yg,    // (B,9,128,128)
    const float* __restrict__ uw,    // (9,9,4,4)  (in,out,kh,kw)
    const float* __restrict__ ub,    // (9)
    const float* __restrict__ LL1,   // (B,3,256,256)
    float* __restrict__ out)         // (B,3,512,512)
{
    __shared__ float ysh[9][18][19];

    const int t    = threadIdx.x;
    const int b    = blockIdx.x >> 6;
    const int tile = blockIdx.x & 63;
    const int r0   = (tile >> 3) << 5;  // 256-res tile origin
    const int c0   = (tile & 7) << 5;
    const int p0   = (r0 >> 1) - 1;     // y row of local 0
    const int q0   = (c0 >> 1) - 1;

    // ---- stage y tile (18x18 halo, 9 ch) into LDS ----
    for (int item = t; item < 9 * 324; item += 256) {
        const int cin = item / 324;
        int rem       = item - cin * 324;
        const int lp  = rem / 18;
        const int lq  = rem - lp * 18;
        const int p   = p0 + lp, q = q0 + lq;
        float v = 0.f;
        if (p >= 0 && p < 128 && q >= 0 && q < 128)
            v = yg[(((size_t)b * 9 + cin) * 128 + p) * 128 + q];
        ysh[cin][lp][lq] = v;
    }
    __syncthreads();

    const int i2 = t >> 4;   // 0..15
    const int j2 = t & 15;   // 0..15

#pragma unroll
    for (int di = 0; di < 2; ++di) {
        float acc[2][9];     // [dj][out-ch] -- only 18 live accumulators
#pragma unroll
        for (int dj = 0; dj < 2; ++dj)
#pragma unroll
            for (int o = 0; o < 9; ++o) acc[dj][o] = ub[o];

#pragma unroll
        for (int cin = 0; cin < 9; ++cin) {
            float yv[2][3];  // rows i2+di+rt, cols j2 + {0,1,2}
#pragma unroll
            for (int rt = 0; rt < 2; ++rt)
#pragma unroll
                for (int c = 0; c < 3; ++c)
                    yv[rt][c] = ysh[cin][i2 + di + rt][j2 + c];
#pragma unroll
            for (int rt = 0; rt < 2; ++rt) {
                const int a = 3 - di - 2 * rt;
#pragma unroll
                for (int dj = 0; dj < 2; ++dj)
#pragma unroll
                    for (int ct = 0; ct < 2; ++ct) {
                        const int kb  = 3 - dj - 2 * ct;
                        const float vv = yv[rt][dj + ct];
#pragma unroll
                        for (int o = 0; o < 9; ++o)
                            acc[dj][o] += vv * uw[cin * 144 + o * 16 + a * 4 + kb];
                    }
            }
        }

        // ---- epilogue for this di: idwt2 -> rows 2I, 2I+1; 4 cols ----
        const int I     = r0 + 2 * i2 + di;
        const int Jbase = c0 + 2 * j2;        // even
#pragma unroll
        for (int cc = 0; cc < 3; ++cc) {
            const float2 llv = *reinterpret_cast<const float2*>(
                LL1 + (((size_t)b * 3 + cc) * 256 + I) * 256 + Jbase);
            float4 top, bot;
            {
                const float ll = llv.x;
                const float lh = acc[0][cc * 3 + 0];
                const float hl = acc[0][cc * 3 + 1];
                const float hh = acc[0][cc * 3 + 2];
                const float e0 = ll + lh, od0 = ll - lh;
                const float e1 = hl + hh, od1 = hl - hh;
                top.x = (e0 + e1) * 0.5f; top.y = (e0 - e1) * 0.5f;
                bot.x = (od0 + od1) * 0.5f; bot.y = (od0 - od1) * 0.5f;
            }
            {
                const float ll = llv.y;
                const float lh = acc[1][cc * 3 + 0];
                const float hl = acc[1][cc * 3 + 1];
                const float hh = acc[1][cc * 3 + 2];
                const float e0 = ll + lh, od0 = ll - lh;
                const float e1 = hl + hh, od1 = hl - hh;
                top.z = (e0 + e1) * 0.5f; top.w = (e0 - e1) * 0.5f;
                bot.z = (od0 + od1) * 0.5f; bot.w = (od0 - od1) * 0.5f;
            }
            float* op = out + (((size_t)b * 3 + cc) * 512 + 2 * I) * 512 + 2 * Jbase;
            *reinterpret_cast<float4*>(op) = top;
            *reinterpret_cast<float4*>(op + 512) = bot;
        }
    }
}

extern "C" void kernel_launch(void* const* d_in, const int* in_sizes, int n_in,
                              void* d_out, int out_size, void* d_ws, size_t ws_size,
                              hipStream_t stream) {
    const float* x  = (const float*)d_in[0];
    const float* dw = (const float*)d_in[1];
    const float* db = (const float*)d_in[2];
    const float* uw = (const float*)d_in[3];
    const float* ub = (const float*)d_in[4];
    float* outp = (float*)d_out;

    float* LL1 = (float*)d_ws;                                // 25.2 MB
    float* y   = LL1 + (size_t)BB * 3 * 256 * 256;            // 18.9 MB

    dim3 blk(256);
    k1_dwt_down<<<dim3(BB * 64), blk, 0, stream>>>(x, dw, db, LL1, y);
    k2_up_idwt<<<dim3(BB * 64), blk, 0, stream>>>(y, uw, ub, LL1, outp);
}

// Round 3
// 93.961 us; speedup vs baseline: 2.7475x; 2.7475x over previous
//
#include <hip/hip_runtime.h>

// ---------------------------------------------------------------------------
// DWT autoencoder round trip. Level-2 dwt2+idwt2 cancel exactly -> LL1r==LL1.
//   K0: rearrange conv weights into exact consumption order (consecutive
//       uniform addresses -> wide s_load, weights ride in SGPRs)
//   K1: haar dwt level1 of x -> LL1 (B,3,256,256)  +  conv3x3 s2 of the
//       9 detail bands -> y (B,9,128,128)
//   K2: convT4x4 s2 of y -> l1 bands, fused with idwt2(LL1, l1) -> out
// B=32, C=3, H=W=512.
// R2 lesson: 36 accumulators @ VGPR=40 -> AGPR shuttle (3x VALU); unrolled
// scattered weight s_loads -> 10x VALU. Fix: reordered weights + VGPR room.
// ---------------------------------------------------------------------------

#define BB 32

// K0: one small block; wd[((cin*3+a)*3+q)*9+o] = dw[o,cin,a,q]
//     wu[((cin*4+rt*2+ct)*4+di*2+dj)*9+o] = uw[cin, o, 3-di-2rt, 3-dj-2ct]
__global__ __launch_bounds__(256) void k0_rearrange(
    const float* __restrict__ dw, const float* __restrict__ uw,
    float* __restrict__ wd, float* __restrict__ wu)
{
    const int t = threadIdx.x;
    for (int i = t; i < 729; i += 256) {
        const int o = i % 9; int r = i / 9;
        const int q = r % 3; r /= 3;
        const int a = r % 3; const int cin = r / 3;
        wd[i] = dw[o * 81 + cin * 9 + a * 3 + q];
    }
    for (int i = t; i < 1296; i += 256) {
        const int o = i % 9; int r = i / 9;
        const int dj = r & 1; const int di = (r >> 1) & 1; r >>= 2;
        const int ct = r & 1; const int rt = (r >> 1) & 1; const int cin = r >> 2;
        wu[i] = uw[cin * 144 + o * 16 + (3 - di - 2 * rt) * 4 + (3 - dj - 2 * ct)];
    }
}

__global__ __launch_bounds__(256) void k1_dwt_down(
    const float* __restrict__ x,     // (B,3,512,512)
    const float* __restrict__ wd,    // reordered (cin,a,q,o)
    const float* __restrict__ db,    // (9)
    float* __restrict__ LL1,         // (B,3,256,256)
    float* __restrict__ y)           // (B,9,128,128)
{
    __shared__ float lvl[9][33][33];   // [c*3+band][row][col], band: LH,HL,HH

    const int t    = threadIdx.x;
    const int b    = blockIdx.x >> 6;
    const int tile = blockIdx.x & 63;
    const int i0   = (tile >> 3) << 4;   // y tile origin (128-res)
    const int j0   = (tile & 7) << 4;
    const int gr0  = 2 * i0 - 1;         // level1 row of local row 0
    const int gc0  = 2 * j0 - 1;

    // ---- stage 1: DWT level 1 into LDS (+ LL1 interior to global) ----
    for (int item = t; item < 3 * 1089; item += 256) {
        const int ch  = item / 1089;
        int rem       = item - ch * 1089;
        const int lr  = rem / 33;
        const int lc  = rem - lr * 33;
        const int r   = gr0 + lr;        // level1 row in [-1, 255]
        const int c   = gc0 + lc;
        float x00 = 0.f, x01 = 0.f, x10 = 0.f, x11 = 0.f;
        if (r >= 0 && c >= 0 && r < 256 && c < 256) {
            const float* xp = x + (((size_t)b * 3 + ch) * 512 + 2 * r) * 512 + 2 * c;
            const float2 v0 = *reinterpret_cast<const float2*>(xp);
            const float2 v1 = *reinterpret_cast<const float2*>(xp + 512);
            x00 = v0.x; x01 = v0.y; x10 = v1.x; x11 = v1.y;
        }
        const float s0 = x00 + x01, d0 = x00 - x01;
        const float s1 = x10 + x11, d1 = x10 - x11;
        lvl[ch * 3 + 0][lr][lc] = (s0 - s1) * 0.5f;  // LH
        lvl[ch * 3 + 1][lr][lc] = (d0 + d1) * 0.5f;  // HL
        lvl[ch * 3 + 2][lr][lc] = (d0 - d1) * 0.5f;  // HH
        if (lr >= 1 && lc >= 1) {
            LL1[(((size_t)b * 3 + ch) * 256 + r) * 256 + c] = (s0 + s1) * 0.5f;
        }
    }
    __syncthreads();

    // ---- stage 2: 3x3 stride-2 conv, 9 in ch -> 9 out ch ----
    const int ti = t >> 4;   // 0..15
    const int tj = t & 15;
    float acc[9];
#pragma unroll
    for (int o = 0; o < 9; ++o) acc[o] = db[o];

    for (int cin = 0; cin < 9; ++cin) {
        float v[3][3];
#pragma unroll
        for (int a = 0; a < 3; ++a)
#pragma unroll
            for (int q = 0; q < 3; ++q)
                v[a][q] = lvl[cin][2 * ti + a][2 * tj + q];
        const float* wc = wd + cin * 81;
#pragma unroll
        for (int a = 0; a < 3; ++a)
#pragma unroll
            for (int q = 0; q < 3; ++q) {
                const float vv = v[a][q];
                const float* wg = wc + (a * 3 + q) * 9;   // 9 consecutive
#pragma unroll
                for (int o = 0; o < 9; ++o)
                    acc[o] += vv * wg[o];
            }
    }
#pragma unroll
    for (int o = 0; o < 9; ++o)
        y[(((size_t)b * 9 + o) * 128 + (i0 + ti)) * 128 + (j0 + tj)] = acc[o];
}

// K2: one block = one batch image, a 32x32 tile at 256-res (=> 64x64 output
// pixels at 512-res), all 3 colors. Each thread owns a 2x2 parity quad; all
// 36 accumulators live (needs VGPR room -> launch_bounds(256,4)).
__global__ __launch_bounds__(256, 4) void k2_up_idwt(
    const float* __restrict__ yg,    // (B,9,128,128)
    const float* __restrict__ wu,    // reordered (cin,rt,ct,di,dj,o)
    const float* __restrict__ ub,    // (9)
    const float* __restrict__ LL1,   // (B,3,256,256)
    float* __restrict__ out)         // (B,3,512,512)
{
    __shared__ float ysh[9][18][19];

    const int t    = threadIdx.x;
    const int b    = blockIdx.x >> 6;
    const int tile = blockIdx.x & 63;
    const int r0   = (tile >> 3) << 5;  // 256-res tile origin
    const int c0   = (tile & 7) << 5;
    const int p0   = (r0 >> 1) - 1;     // y row of local 0
    const int q0   = (c0 >> 1) - 1;

    // ---- stage y tile (18x18 halo, 9 ch) into LDS ----
    for (int item = t; item < 9 * 324; item += 256) {
        const int cin = item / 324;
        int rem       = item - cin * 324;
        const int lp  = rem / 18;
        const int lq  = rem - lp * 18;
        const int p   = p0 + lp, q = q0 + lq;
        float v = 0.f;
        if (p >= 0 && p < 128 && q >= 0 && q < 128)
            v = yg[(((size_t)b * 9 + cin) * 128 + p) * 128 + q];
        ysh[cin][lp][lq] = v;
    }
    __syncthreads();

    const int i2 = t >> 4;   // 0..15
    const int j2 = t & 15;   // 0..15

    float acc[2][2][9];      // [di][dj][out-ch]
#pragma unroll
    for (int di = 0; di < 2; ++di)
#pragma unroll
        for (int dj = 0; dj < 2; ++dj)
#pragma unroll
            for (int o = 0; o < 9; ++o) acc[di][dj][o] = ub[o];

    for (int cin = 0; cin < 9; ++cin) {
        float yv[3][3];
#pragma unroll
        for (int r = 0; r < 3; ++r)
#pragma unroll
            for (int c = 0; c < 3; ++c)
                yv[r][c] = ysh[cin][i2 + r][j2 + c];
        const float* wc = wu + cin * 144;
#pragma unroll
        for (int rt = 0; rt < 2; ++rt)
#pragma unroll
            for (int ct = 0; ct < 2; ++ct) {
                const float* wg = wc + (rt * 2 + ct) * 36;  // 36 consecutive
#pragma unroll
                for (int di = 0; di < 2; ++di)
#pragma unroll
                    for (int dj = 0; dj < 2; ++dj) {
                        const float vv = yv[di + rt][dj + ct];
                        const float* w9 = wg + (di * 2 + dj) * 9;
#pragma unroll
                        for (int o = 0; o < 9; ++o)
                            acc[di][dj][o] += vv * w9[o];
                    }
            }
    }

    // ---- epilogue: idwt2(LL1, LH, HL, HH) -> 4x4 output pixels / color ----
#pragma unroll
    for (int cc = 0; cc < 3; ++cc) {
#pragma unroll
        for (int di = 0; di < 2; ++di) {
            const int I = r0 + 2 * i2 + di;
            const int J = c0 + 2 * j2;
            const float2 llv = *reinterpret_cast<const float2*>(
                LL1 + (((size_t)b * 3 + cc) * 256 + I) * 256 + J);
            float4 top, bot;
            {
                const float ll = llv.x;
                const float lh = acc[di][0][cc * 3 + 0];
                const float hl = acc[di][0][cc * 3 + 1];
                const float hh = acc[di][0][cc * 3 + 2];
                const float e0 = ll + lh, od0 = ll - lh;
                const float e1 = hl + hh, od1 = hl - hh;
                top.x = (e0 + e1) * 0.5f; top.y = (e0 - e1) * 0.5f;
                bot.x = (od0 + od1) * 0.5f; bot.y = (od0 - od1) * 0.5f;
            }
            {
                const float ll = llv.y;
                const float lh = acc[di][1][cc * 3 + 0];
                const float hl = acc[di][1][cc * 3 + 1];
                const float hh = acc[di][1][cc * 3 + 2];
                const float e0 = ll + lh, od0 = ll - lh;
                const float e1 = hl + hh, od1 = hl - hh;
                top.z = (e0 + e1) * 0.5f; top.w = (e0 - e1) * 0.5f;
                bot.z = (od0 + od1) * 0.5f; bot.w = (od0 - od1) * 0.5f;
            }
            float* op = out + (((size_t)b * 3 + cc) * 512 + 2 * I) * 512 + 2 * J;
            *reinterpret_cast<float4*>(op) = top;
            *reinterpret_cast<float4*>(op + 512) = bot;
        }
    }
}

extern "C" void kernel_launch(void* const* d_in, const int* in_sizes, int n_in,
                              void* d_out, int out_size, void* d_ws, size_t ws_size,
                              hipStream_t stream) {
    const float* x  = (const float*)d_in[0];
    const float* dw = (const float*)d_in[1];
    const float* db = (const float*)d_in[2];
    const float* uw = (const float*)d_in[3];
    const float* ub = (const float*)d_in[4];
    float* outp = (float*)d_out;

    float* wsf = (float*)d_ws;
    float* wd  = wsf;            // 729 floats (pad to 768)
    float* wu  = wsf + 768;      // 1296 floats (pad to 1536)
    float* LL1 = wsf + 2304;                         // 25.2 MB
    float* y   = LL1 + (size_t)BB * 3 * 256 * 256;   // 18.9 MB

    k0_rearrange<<<dim3(1), dim3(256), 0, stream>>>(dw, uw, wd, wu);
    k1_dwt_down<<<dim3(BB * 64), dim3(256), 0, stream>>>(x, wd, db, LL1, y);
    k2_up_idwt<<<dim3(BB * 64), dim3(256), 0, stream>>>(y, wu, ub, LL1, outp);
}